// Round 4
// baseline (993.034 us; speedup 1.0000x reference)
//
#include <hip/hip_runtime.h>
#include <cmath>

#define BB 4
#define SS 256
#define ZDIM 128
#define GCH 256
#define NBLKS 8
#define NPIX 65536   // 256*256
#define U1C 128      // GC/2

__device__ __forceinline__ float lrelu(float x){ return x >= 0.f ? x : 0.2f*x; }

__device__ __forceinline__ void spin_wait(int* p, int target){
  while(__hip_atomic_load(p, __ATOMIC_ACQUIRE, __HIP_MEMORY_SCOPE_AGENT) < target)
    __builtin_amdgcn_s_sleep(2);
}
__device__ __forceinline__ void signal_add(int* p){
  __hip_atomic_fetch_add(p, 1, __ATOMIC_RELEASE, __HIP_MEMORY_SCOPE_AGENT);
}

// ---- segment mean pooling (LDS histogram, then global atomics) ----
__global__ void k_pool(const float* __restrict__ img, const int* __restrict__ seg,
                       float* __restrict__ segsum, float* __restrict__ counts){
  __shared__ float ls[SS*4];
  int t = threadIdx.x;
  for(int j=t;j<SS*4;j+=256) ls[j]=0.f;
  __syncthreads();
  int b = blockIdx.x >> 6;            // 64 blocks per batch
  int base = blockIdx.x*1024;
  for(int it=0; it<4; it++){
    int idx = base + it*256 + t;
    int n = idx & (NPIX-1);
    int s = seg[idx];
    atomicAdd(&ls[s*4+0], img[(b*3+0)*NPIX+n]);
    atomicAdd(&ls[s*4+1], img[(b*3+1)*NPIX+n]);
    atomicAdd(&ls[s*4+2], img[(b*3+2)*NPIX+n]);
    atomicAdd(&ls[s*4+3], 1.0f);
  }
  __syncthreads();
  for(int j=t;j<SS*4;j+=256){
    int s = j>>2, c = j&3;
    float vv = ls[j];
    if(vv != 0.f){
      if(c<3) atomicAdd(&segsum[(b*SS+s)*3+c], vv);
      else    atomicAdd(&counts[b*SS+s], vv);
    }
  }
}

// ---- prep1: transpose A and up1_w ----
__global__ void k_prep1(const float* __restrict__ A, const float* __restrict__ w1,
                        float* __restrict__ At, float* __restrict__ wT){
  int idx = blockIdx.x*256 + threadIdx.x;   // 262144 + 294912 = 557056
  if(idx < 262144){
    int b = idx >> 16; int r = idx & 65535; int i = r >> 8; int j = r & 255;
    At[(b*SS + j)*SS + i] = A[idx];
  } else {
    int t = idx - 262144;                   // wT[(k*256+c)*128+o] = w1[(o*256+c)*9+k]
    int o = t & 127; int r = t >> 7; int c = r & 255; int k = r >> 8;
    wT[t] = w1[(o*GCH + c)*9 + k];
  }
}

// ---- x0 = WSproj(concat(feats, z)) -> xprime (block-0 input, no AdaIN) ----
__global__ void k_x0(const float* __restrict__ segsum, const float* __restrict__ counts,
                     const float* __restrict__ z, const float* __restrict__ pw,
                     const float* __restrict__ pb, float sc, float* __restrict__ xp){
  int i = blockIdx.x*64 + (threadIdx.x & 63);
  int o = blockIdx.y*4  + (threadIdx.x >> 6);
  int b = blockIdx.z;
  float cnt = counts[b*SS+i] + 1e-6f;
  float f0 = segsum[(b*SS+i)*3+0]/cnt;
  float f1 = segsum[(b*SS+i)*3+1]/cnt;
  float f2 = segsum[(b*SS+i)*3+2]/cnt;
  const float* wr = pw + o*131;
  float acc = wr[0]*f0 + wr[1]*f1 + wr[2]*f2;
  const float* zb = z + b*ZDIM;
  for(int j=0;j<ZDIM;j++) acc += wr[3+j]*zb[j];
  xp[(b*GCH+o)*SS + i] = acc*sc + pb[o];
}

// ---- one graph iteration: gemm(512) -> styleL1(32) -> styleL2+apply(32) ----
// xp: pre-activated input [B][GC][S]; h2: raw propagated output; xp updated in place
__global__ __launch_bounds__(256) void k_iter(float* __restrict__ xp,
        float* __restrict__ h2, float* __restrict__ m, float* __restrict__ s1g,
        const float* __restrict__ At,
        const float* __restrict__ bw, const float* __restrict__ bb,
        const float* __restrict__ a1w, const float* __restrict__ a1b,
        const float* __restrict__ a2w, const float* __restrict__ a2b,
        float sc, float sc1, float sc2, int it, int* __restrict__ cnt){
  __shared__ float sh[520];
  int id = blockIdx.x;
  int tid = threadIdx.x;
  int lane = tid & 63, wv = tid >> 6;

  if(id < 512){
    // ---- gemm role: channels c0,c0+1 of batch b ----
    int b = id & 3;
    int c0 = (id >> 2)*2;
    const float* x = xp + b*GCH*SS + tid;          // thread = node j
    const float* w0 = bw + c0*GCH;                 // wave-uniform -> s_load
    const float* w1 = w0 + GCH;
    float a0 = 0.f, a1 = 0.f;
    #pragma unroll 8
    for(int k=0;k<GCH;k++){
      float xv = x[k*SS];
      a0 += w0[k]*xv;
      a1 += w1[k]*xv;
    }
    sh[tid*2]   = a0*sc + bb[c0];
    sh[tid*2+1] = a1*sc + bb[c0+1];
    __syncthreads();
    const float* ab = At + b*SS*SS + tid;
    float r0 = 0.f, r1 = 0.f;
    #pragma unroll 8
    for(int jj=0;jj<SS;jj++){
      float av = ab[jj*SS];
      float2 hp = *(const float2*)&sh[jj*2];
      r0 += hp.x*av; r1 += hp.y*av;
    }
    h2[(b*GCH+c0)*SS + tid]   = r0;
    h2[(b*GCH+c0+1)*SS + tid] = r1;
    float s0 = r0, s1v = r1;
    for(int off=32; off; off>>=1){ s0 += __shfl_down(s0,off); s1v += __shfl_down(s1v,off); }
    __syncthreads();
    if(lane==0){ sh[512 + wv*2] = s0; sh[512 + wv*2 + 1] = s1v; }
    __syncthreads();
    if(tid==0){
      m[b*GCH+c0]   = (sh[512]+sh[514]+sh[516]+sh[518])*(1.f/256.f);
      m[b*GCH+c0+1] = (sh[513]+sh[515]+sh[517]+sh[519])*(1.f/256.f);
    }
    __syncthreads();
    if(tid==0) signal_add(&cnt[it*4 + b]);
  } else if(id < 544){
    // ---- style layer 1: 8 blocks per batch, 64 rows each ----
    int rid = id - 512;
    int b = rid & 3, q = rid >> 2;
    if(tid==0) spin_wait(&cnt[it*4 + b], 128);
    __syncthreads();
    float4 mv = *(const float4*)(m + b*GCH + lane*4);
    #pragma unroll 4
    for(int r=0;r<16;r++){
      int row = q*64 + wv*16 + r;
      float4 w4 = *(const float4*)(a1w + row*GCH + lane*4);
      float p = w4.x*mv.x + w4.y*mv.y + w4.z*mv.z + w4.w*mv.w;
      for(int off=32; off; off>>=1) p += __shfl_xor(p, off);
      if(lane==0) s1g[b*512 + row] = lrelu(p*sc1 + a1b[row]);
    }
    __syncthreads();
    if(tid==0) signal_add(&cnt[32 + it*4 + b]);
  } else {
    // ---- style layer 2 + AdaIN apply: 8 blocks per batch, 32 channels each ----
    int rid = id - 544;
    int b = rid & 3, q = rid >> 2;
    if(tid==0) spin_wait(&cnt[32 + it*4 + b], 8);
    __syncthreads();
    float4 sa = *(const float4*)(s1g + b*512 + lane*8);
    float4 sb = *(const float4*)(s1g + b*512 + lane*8 + 4);
    #pragma unroll 4
    for(int r=0;r<16;r++){
      int lr = wv*16 + r;                 // 0..63
      int cc = lr & 31;
      int t  = (lr < 32) ? (q*32 + cc) : (256 + q*32 + cc);
      const float* wr = a2w + t*512 + lane*8;
      float4 wa = *(const float4*)wr;
      float4 wb4 = *(const float4*)(wr+4);
      float p = wa.x*sa.x + wa.y*sa.y + wa.z*sa.z + wa.w*sa.w
              + wb4.x*sb.x + wb4.y*sb.y + wb4.z*sb.z + wb4.w*sb.w;
      for(int off=32; off; off>>=1) p += __shfl_xor(p, off);
      if(lane==0) sh[(lr<32 ? cc : 32+cc)] = p*sc2 + a2b[t];
    }
    __syncthreads();
    // apply AdaIN + leaky in place -> xp becomes next iteration's input
    #pragma unroll 4
    for(int cc=0;cc<32;cc++){
      int c = q*32 + cc;
      float ga = sh[cc], be = sh[32+cc];
      float hv = h2[(b*GCH+c)*SS + tid];
      xp[(b*GCH+c)*SS + tid] = lrelu(ga*hv + be);
    }
  }
}

// ---- v[b][k][s][o] = sum_c wT[k][c][o] * xp[c][s] (xp already activated) ----
__global__ __launch_bounds__(256) void k_v(const float* __restrict__ xf,
        const float4* __restrict__ wT4, float4* __restrict__ v4){
  int s0 = blockIdx.x*8;
  int k  = blockIdx.y;
  int b  = blockIdx.z;
  int tid = threadIdx.x;
  __shared__ float xft[256][8];
  for(int t = tid; t < 2048; t += 256){
    int c = t>>3, ss = t&7;
    xft[c][ss] = xf[(b*GCH+c)*SS + s0 + ss];
  }
  __syncthreads();
  int og = tid & 31, s = tid >> 5;
  const float4* wb = wT4 + (size_t)k*GCH*32 + og;
  float4 acc = {0.f,0.f,0.f,0.f};
  #pragma unroll 4
  for(int c=0;c<GCH;c++){
    float xv = xft[c][s];
    float4 w = wb[c*32];
    acc.x += w.x*xv; acc.y += w.y*xv; acc.z += w.z*xv; acc.w += w.w*xv;
  }
  v4[((size_t)(b*9+k)*SS + s0 + s)*32 + og] = acc;
}

// ---- fused conv1-gather(float4) + conv2 partial (32-ch group), atomic y2 ----
__global__ __launch_bounds__(256) void k_conv(const float4* __restrict__ v4,
        const int* __restrict__ seg, const float4* __restrict__ b14,
        const float* __restrict__ w2, float* __restrict__ y2){
  __shared__ float y1t[32*101];     // [ci][pp] transposed
  __shared__ int   segl[144];
  __shared__ float w2l[864];
  __shared__ float part[768];
  int x0p = blockIdx.x*8, y0p = blockIdx.y*8;
  int b = blockIdx.z >> 2, g = blockIdx.z & 3;
  int tid = threadIdx.x;
  if(tid < 144){
    int r = tid/12, cc = tid%12;
    int gy = y0p - 2 + r, gx = x0p - 2 + cc;
    segl[tid] = (gy>=0 && gy<256 && gx>=0 && gx<256) ? seg[(b*256+gy)*256+gx] : -1;
  }
  for(int t=tid; t<864; t+=256){
    int oc = t/288, rem = t%288;
    w2l[t] = w2[oc*1152 + g*288 + rem];
  }
  __syncthreads();
  int o4 = tid & 7;
  const float4* vb = v4 + (size_t)(b*9)*SS*32 + g*8 + o4;
  float4 bias = b14[g*8 + o4];
  for(int task = tid; task < 800; task += 256){
    int pp = task >> 3;
    int py = pp/10, px = pp%10;
    int gy = y0p - 1 + py, gx = x0p - 1 + px;
    float4 acc = {0.f,0.f,0.f,0.f};
    if(gy>=0 && gy<256 && gx>=0 && gx<256){
      acc = bias;
      #pragma unroll
      for(int k=0;k<9;k++){
        int sidx = segl[(py + k/3)*12 + (px + k%3)];
        if(sidx >= 0){
          float4 vv = vb[(k*SS + sidx)*32];
          acc.x += vv.x; acc.y += vv.y; acc.z += vv.z; acc.w += vv.w;
        }
      }
      acc.x = lrelu(acc.x); acc.y = lrelu(acc.y); acc.z = lrelu(acc.z); acc.w = lrelu(acc.w);
    }
    int c0 = o4*4;
    y1t[(c0+0)*101+pp] = acc.x;
    y1t[(c0+1)*101+pp] = acc.y;
    y1t[(c0+2)*101+pp] = acc.z;
    y1t[(c0+3)*101+pp] = acc.w;
  }
  __syncthreads();
  int pxo = tid & 63, sg = tid >> 6;
  int ty = pxo >> 3, tx = pxo & 7;
  float p0=0.f,p1=0.f,p2=0.f;
  for(int k=0;k<9;k++){
    int pp0 = (ty + k/3)*10 + (tx + k%3);
    #pragma unroll
    for(int cc=0;cc<8;cc++){
      int ci = sg*8+cc;
      float yv = y1t[ci*101 + pp0];
      p0 += w2l[(0*32+ci)*9+k]*yv;
      p1 += w2l[(1*32+ci)*9+k]*yv;
      p2 += w2l[(2*32+ci)*9+k]*yv;
    }
  }
  part[tid]     = p0;
  part[256+tid] = p1;
  part[512+tid] = p2;
  __syncthreads();
  if(tid < 64){
    float s0 = part[tid]    +part[tid+64]    +part[tid+128]    +part[tid+192];
    float s1 = part[256+tid]+part[256+tid+64]+part[256+tid+128]+part[256+tid+192];
    float s2 = part[512+tid]+part[512+tid+64]+part[512+tid+128]+part[512+tid+192];
    int gy = y0p + (tid>>3), gx = x0p + (tid&7);
    int nidx = gy*256+gx;
    atomicAdd(&y2[(b*3+0)*NPIX+nidx], s0);
    atomicAdd(&y2[(b*3+1)*NPIX+nidx], s1);
    atomicAdd(&y2[(b*3+2)*NPIX+nidx], s2);
  }
}

// ---- per (b,channel) sum & sumsq, parallel chunks with f64 atomics ----
__global__ void k_stats(const float* __restrict__ y2, double* __restrict__ stats){
  int bc = blockIdx.x;     // 12
  int chunk = blockIdx.y;  // 8
  const float* p = y2 + (size_t)bc*NPIX + chunk*8192;
  int t = threadIdx.x;
  double s=0.0, q=0.0;
  for(int i=t;i<8192;i+=256){ double vv = (double)p[i]; s+=vv; q+=vv*vv; }
  __shared__ double rs[256], rq[256];
  rs[t]=s; rq[t]=q; __syncthreads();
  for(int st=128; st; st>>=1){ if(t<st){rs[t]+=rs[t+st]; rq[t]+=rq[t+st];} __syncthreads(); }
  if(t==0){ atomicAdd(&stats[bc*2], rs[0]); atomicAdd(&stats[bc*2+1], rq[0]); }
}

// ---- instance norm + tanh ----
__global__ void k_norm(const float* __restrict__ y2, const double* __restrict__ stats,
                       float* __restrict__ out){
  int idx = blockIdx.x*256+threadIdx.x;
  int bu = idx >> 16;
  double mu  = stats[bu*2+0] * (1.0/65536.0);
  double ex2 = stats[bu*2+1] * (1.0/65536.0);
  double var = ex2 - mu*mu;
  float inv = (float)(1.0/sqrt(var + 1e-5));
  float mf = (float)mu;
  out[idx] = tanhf((y2[idx]-mf)*inv);
}

extern "C" void kernel_launch(void* const* d_in, const int* in_sizes, int n_in,
                              void* d_out, int out_size, void* d_ws, size_t ws_size,
                              hipStream_t stream) {
  const float* z   = (const float*)d_in[0];
  const float* img = (const float*)d_in[1];
  const int*   seg = (const int*)d_in[2];
  const float* A   = (const float*)d_in[3];
  const float* pw  = (const float*)d_in[4];
  const float* pb  = (const float*)d_in[5];
  const float* bw  = (const float*)d_in[6];
  const float* bb  = (const float*)d_in[7];
  const float* a1w = (const float*)d_in[8];
  const float* a1b = (const float*)d_in[9];
  const float* a2w = (const float*)d_in[10];
  const float* a2b = (const float*)d_in[11];
  const float* w1  = (const float*)d_in[12];
  const float* b1  = (const float*)d_in[13];
  const float* w2  = (const float*)d_in[14];
  const float* b2  = (const float*)d_in[15]; (void)b2; // cancels under InstanceNorm
  float* out = (float*)d_out;

  float* ws = (float*)d_ws;
  float* segsum = ws;                    // 3072
  float* counts = ws + 3072;             // 1024
  float* m      = ws + 4096;             // 1024
  float* s1g    = ws + 5120;             // 2048
  double* stats = (double*)(ws + 7168);  // 24 doubles -> 7216
  int*   cnt    = (int*)(ws + 7216);     // 64 ints -> 7280
  float* xp  = ws + 7296;                // 262144
  float* h2  = xp + 262144;              // 262144
  float* At  = h2 + 262144;              // 262144
  float* wT  = At + 262144;              // 294912
  float* v   = wT + 294912;              // 1179648
  float* y2  = v + 1179648;              // 786432  (end ~12.2 MB)

  hipMemsetAsync(ws, 0, 7296*sizeof(float), stream);     // sums + stats + counters
  hipMemsetAsync(y2, 0, 786432*sizeof(float), stream);   // conv2 accumulator

  float sProj = (float)sqrt(2.0/131.0);
  float s256  = (float)sqrt(2.0/256.0);
  float s512  = (float)sqrt(2.0/512.0);

  k_pool <<<256, 256, 0, stream>>>(img, seg, segsum, counts);
  k_prep1<<<2176, 256, 0, stream>>>(A, w1, At, wT);
  k_x0   <<<dim3(4,64,4), 256, 0, stream>>>(segsum, counts, z, pw, pb, sProj, xp);

  for(int blk=0; blk<NBLKS; blk++){
    k_iter<<<576, 256, 0, stream>>>(xp, h2, m, s1g, At,
                                    bw + blk*GCH*GCH, bb + blk*GCH,
                                    a1w + blk*512*GCH, a1b + blk*512,
                                    a2w + blk*512*512, a2b + blk*512,
                                    s256, s256, s512, blk, cnt);
  }

  k_v   <<<dim3(32,9,4), 256, 0, stream>>>(xp, (const float4*)wT, (float4*)v);
  k_conv<<<dim3(32,32,16), 256, 0, stream>>>((const float4*)v, seg, (const float4*)b1, w2, y2);
  k_stats<<<dim3(12,8), 256, 0, stream>>>(y2, stats);
  k_norm<<<3072, 256, 0, stream>>>(y2, stats, out);
}

// Round 5
// 810.110 us; speedup vs baseline: 1.2258x; 1.2258x over previous
//
#include <hip/hip_runtime.h>
#include <cmath>

#define BB 4
#define SS 256
#define ZDIM 128
#define GCH 256
#define NBLKS 8
#define NPIX 65536   // 256*256
#define U1C 128      // GC/2

__device__ __forceinline__ float lrelu(float x){ return x >= 0.f ? x : 0.2f*x; }

// ---- segment mean pooling (LDS histogram, then global atomics) ----
__global__ void k_pool(const float* __restrict__ img, const int* __restrict__ seg,
                       float* __restrict__ segsum, float* __restrict__ counts){
  __shared__ float ls[SS*4];
  int t = threadIdx.x;
  for(int j=t;j<SS*4;j+=256) ls[j]=0.f;
  __syncthreads();
  int b = blockIdx.x >> 6;            // 64 blocks per batch
  int base = blockIdx.x*1024;
  for(int it=0; it<4; it++){
    int idx = base + it*256 + t;
    int n = idx & (NPIX-1);
    int s = seg[idx];
    atomicAdd(&ls[s*4+0], img[(b*3+0)*NPIX+n]);
    atomicAdd(&ls[s*4+1], img[(b*3+1)*NPIX+n]);
    atomicAdd(&ls[s*4+2], img[(b*3+2)*NPIX+n]);
    atomicAdd(&ls[s*4+3], 1.0f);
  }
  __syncthreads();
  for(int j=t;j<SS*4;j+=256){
    int s = j>>2, c = j&3;
    float vv = ls[j];
    if(vv != 0.f){
      if(c<3) atomicAdd(&segsum[(b*SS+s)*3+c], vv);
      else    atomicAdd(&counts[b*SS+s], vv);
    }
  }
}

// ---- prep1: transpose A (coalesced writes) and up1_w ----
__global__ void k_prep1(const float* __restrict__ A, const float* __restrict__ w1,
                        float* __restrict__ At, float* __restrict__ wT){
  int idx = blockIdx.x*256 + threadIdx.x;   // 262144 + 294912 = 557056
  if(idx < 262144){
    int b = idx >> 16; int r = idx & 65535; int j = r >> 8; int i = r & 255;
    At[idx] = A[(b<<16) + (i<<8) + j];      // At[b][j][i] = A[b][i][j]
  } else {
    int t = idx - 262144;                   // wT[(k*256+c)*128+o] = w1[(o*256+c)*9+k]
    int o = t & 127; int r = t >> 7; int c = r & 255; int k = r >> 8;
    wT[t] = w1[(o*GCH + c)*9 + k];
  }
}

// ---- x0 = WSproj(concat(feats, z)) -> xp (block-0 input, no AdaIN) ----
__global__ void k_x0(const float* __restrict__ segsum, const float* __restrict__ counts,
                     const float* __restrict__ z, const float* __restrict__ pw,
                     const float* __restrict__ pb, float sc, float* __restrict__ xp){
  int i = blockIdx.x*64 + (threadIdx.x & 63);
  int o = blockIdx.y*4  + (threadIdx.x >> 6);
  int b = blockIdx.z;
  float cnt = counts[b*SS+i] + 1e-6f;
  float f0 = segsum[(b*SS+i)*3+0]/cnt;
  float f1 = segsum[(b*SS+i)*3+1]/cnt;
  float f2 = segsum[(b*SS+i)*3+2]/cnt;
  const float* wr = pw + o*131;
  float acc = wr[0]*f0 + wr[1]*f1 + wr[2]*f2;
  const float* zb = z + b*ZDIM;
  for(int j=0;j<ZDIM;j++) acc += wr[3+j]*zb[j];
  xp[(b*GCH+o)*SS + i] = acc*sc + pb[o];
}

// ---- gemm + A-propagation + node mean: 4 channels per block, 512 threads ----
__global__ __launch_bounds__(512) void k_gemm(const float* __restrict__ xp,
        const float* __restrict__ bw, const float* __restrict__ bb,
        const float* __restrict__ At, float sc,
        float* __restrict__ h2, float* __restrict__ m){
  int c0 = blockIdx.x*4;
  int b  = blockIdx.y;
  int j  = threadIdx.x & 255;
  int half = threadIdx.x >> 8;
  __shared__ float wl[4][256];
  __shared__ float h1l[4][260];
  __shared__ float red[4][4];
  wl[half*2+0][j] = bw[(c0+half*2+0)*GCH + j];
  wl[half*2+1][j] = bw[(c0+half*2+1)*GCH + j];
  __syncthreads();
  const float* xb = xp + b*GCH*SS + j;
  float a0 = 0.f, a1 = 0.f;
  int ch = half*2;
  #pragma unroll 4
  for(int k=0;k<GCH;k++){
    float xv = xb[k*SS];
    a0 += wl[ch][k]*xv;
    a1 += wl[ch+1][k]*xv;
  }
  h1l[ch][j]   = a0*sc + bb[c0+ch];
  h1l[ch+1][j] = a1*sc + bb[c0+ch+1];
  __syncthreads();
  const float* ab = At + b*SS*SS + j;
  float r0 = 0.f, r1 = 0.f;
  for(int jj=0;jj<SS;jj+=4){
    float4 h0 = *(const float4*)&h1l[ch][jj];
    float4 h1v = *(const float4*)&h1l[ch+1][jj];
    float av0 = ab[jj*SS], av1 = ab[(jj+1)*SS], av2 = ab[(jj+2)*SS], av3 = ab[(jj+3)*SS];
    r0 += h0.x*av0 + h0.y*av1 + h0.z*av2 + h0.w*av3;
    r1 += h1v.x*av0 + h1v.y*av1 + h1v.z*av2 + h1v.w*av3;
  }
  h2[(b*GCH+c0+ch)*SS + j]   = r0;
  h2[(b*GCH+c0+ch+1)*SS + j] = r1;
  float s0 = r0, s1v = r1;
  for(int off=32; off; off>>=1){ s0 += __shfl_down(s0,off); s1v += __shfl_down(s1v,off); }
  int w3 = (threadIdx.x >> 6) & 3;
  if((j&63)==0){ red[ch][w3] = s0; red[ch+1][w3] = s1v; }
  __syncthreads();
  if(threadIdx.x < 4)
    m[b*GCH + c0 + threadIdx.x] =
      (red[threadIdx.x][0]+red[threadIdx.x][1]+red[threadIdx.x][2]+red[threadIdx.x][3])*(1.f/256.f);
}

// ---- style layer 1: 32 blocks, 16 rows each, all 4 batches per row ----
__global__ __launch_bounds__(256) void k_s1(const float* __restrict__ m,
        const float* __restrict__ a1w, const float* __restrict__ a1b,
        float sc1, float* __restrict__ s1g){
  int q = blockIdx.x;               // 0..31
  int lane = threadIdx.x & 63, wv = threadIdx.x >> 6;
  float4 mv0 = *(const float4*)(m + 0*GCH + lane*4);
  float4 mv1 = *(const float4*)(m + 1*GCH + lane*4);
  float4 mv2 = *(const float4*)(m + 2*GCH + lane*4);
  float4 mv3 = *(const float4*)(m + 3*GCH + lane*4);
  #pragma unroll
  for(int r=0;r<4;r++){
    int row = q*16 + wv*4 + r;
    float4 w4 = *(const float4*)(a1w + row*GCH + lane*4);
    float p0 = w4.x*mv0.x + w4.y*mv0.y + w4.z*mv0.z + w4.w*mv0.w;
    float p1 = w4.x*mv1.x + w4.y*mv1.y + w4.z*mv1.z + w4.w*mv1.w;
    float p2 = w4.x*mv2.x + w4.y*mv2.y + w4.z*mv2.z + w4.w*mv2.w;
    float p3 = w4.x*mv3.x + w4.y*mv3.y + w4.z*mv3.z + w4.w*mv3.w;
    for(int off=32; off; off>>=1){
      p0 += __shfl_xor(p0,off); p1 += __shfl_xor(p1,off);
      p2 += __shfl_xor(p2,off); p3 += __shfl_xor(p3,off);
    }
    if(lane < 4){
      float p = lane==0 ? p0 : lane==1 ? p1 : lane==2 ? p2 : p3;
      s1g[lane*512 + row] = lrelu(p*sc1 + a1b[row]);
    }
  }
}

// ---- style layer 2 + AdaIN apply: 32 blocks, 8 channels each, all batches ----
__global__ __launch_bounds__(256) void k_s2apply(const float* __restrict__ s1g,
        const float* __restrict__ a2w, const float* __restrict__ a2b,
        const float* __restrict__ h2, float sc2, float* __restrict__ xp){
  int q = blockIdx.x;               // 0..31 -> channels q*8..q*8+7
  int tid = threadIdx.x;
  int lane = tid & 63, wv = tid >> 6;
  __shared__ float gbl[4][16];      // [b][0..7]=gamma, [8..15]=beta
  // stage s1 slice into registers: 8 floats per lane per batch
  float4 sa[4], sb[4];
  #pragma unroll
  for(int b=0;b<4;b++){
    sa[b] = *(const float4*)(s1g + b*512 + lane*8);
    sb[b] = *(const float4*)(s1g + b*512 + lane*8 + 4);
  }
  #pragma unroll
  for(int r=0;r<4;r++){
    int ridx = wv*4 + r;            // 0..15
    int cc = ridx & 7;
    int t = (ridx < 8) ? (q*8 + cc) : (256 + q*8 + cc);
    const float* wr = a2w + t*512 + lane*8;
    float4 wa = *(const float4*)wr;
    float4 wb4 = *(const float4*)(wr+4);
    float p0 = wa.x*sa[0].x+wa.y*sa[0].y+wa.z*sa[0].z+wa.w*sa[0].w
             + wb4.x*sb[0].x+wb4.y*sb[0].y+wb4.z*sb[0].z+wb4.w*sb[0].w;
    float p1 = wa.x*sa[1].x+wa.y*sa[1].y+wa.z*sa[1].z+wa.w*sa[1].w
             + wb4.x*sb[1].x+wb4.y*sb[1].y+wb4.z*sb[1].z+wb4.w*sb[1].w;
    float p2 = wa.x*sa[2].x+wa.y*sa[2].y+wa.z*sa[2].z+wa.w*sa[2].w
             + wb4.x*sb[2].x+wb4.y*sb[2].y+wb4.z*sb[2].z+wb4.w*sb[2].w;
    float p3 = wa.x*sa[3].x+wa.y*sa[3].y+wa.z*sa[3].z+wa.w*sa[3].w
             + wb4.x*sb[3].x+wb4.y*sb[3].y+wb4.z*sb[3].z+wb4.w*sb[3].w;
    for(int off=32; off; off>>=1){
      p0 += __shfl_xor(p0,off); p1 += __shfl_xor(p1,off);
      p2 += __shfl_xor(p2,off); p3 += __shfl_xor(p3,off);
    }
    if(lane < 4){
      float p = lane==0 ? p0 : lane==1 ? p1 : lane==2 ? p2 : p3;
      gbl[lane][ridx] = p*sc2 + a2b[t];
    }
  }
  __syncthreads();
  int c0 = q*8;
  #pragma unroll
  for(int b=0;b<4;b++){
    #pragma unroll
    for(int cc=0;cc<8;cc++){
      float ga = gbl[b][cc], be = gbl[b][8+cc];
      float hv = h2[(b*GCH + c0+cc)*SS + tid];
      xp[(b*GCH + c0+cc)*SS + tid] = lrelu(ga*hv + be);
    }
  }
}

// ---- v[b][k][s][o] = sum_c wT[k][c][o] * xp[c][s] (xp already activated) ----
__global__ __launch_bounds__(256) void k_v(const float* __restrict__ xf,
        const float4* __restrict__ wT4, float4* __restrict__ v4){
  int s0 = blockIdx.x*8;
  int k  = blockIdx.y;
  int b  = blockIdx.z;
  int tid = threadIdx.x;
  __shared__ float xft[256][8];
  for(int t = tid; t < 2048; t += 256){
    int c = t>>3, ss = t&7;
    xft[c][ss] = xf[(b*GCH+c)*SS + s0 + ss];
  }
  __syncthreads();
  int og = tid & 31, s = tid >> 5;
  const float4* wb = wT4 + (size_t)k*GCH*32 + og;
  float4 acc = {0.f,0.f,0.f,0.f};
  #pragma unroll 4
  for(int c=0;c<GCH;c++){
    float xv = xft[c][s];
    float4 w = wb[c*32];
    acc.x += w.x*xv; acc.y += w.y*xv; acc.z += w.z*xv; acc.w += w.w*xv;
  }
  v4[((size_t)(b*9+k)*SS + s0 + s)*32 + og] = acc;
}

// ---- fused conv1-gather(float4) + conv2, 16x16 tile, 32-ch group ----
__global__ __launch_bounds__(256) void k_conv(const float4* __restrict__ v4,
        const int* __restrict__ seg, const float4* __restrict__ b14,
        const float* __restrict__ w2, float* __restrict__ y2){
  __shared__ float y1t[324*36];     // [pp][9 float4], slot 8 unused pad
  __shared__ int   segl[400];
  __shared__ float w2l[864];
  int x0p = blockIdx.x*16, y0p = blockIdx.y*16;
  int b = blockIdx.z >> 2, g = blockIdx.z & 3;
  int tid = threadIdx.x;
  for(int t=tid; t<400; t+=256){
    int r = t/20, cc = t%20;
    int gy = y0p - 2 + r, gx = x0p - 2 + cc;
    segl[t] = (gy>=0 && gy<256 && gx>=0 && gx<256) ? seg[(b*256+gy)*256+gx] : -1;
  }
  for(int t=tid; t<864; t+=256){
    int oc = t/288, rem = t%288;
    w2l[t] = w2[oc*1152 + g*288 + rem];
  }
  __syncthreads();
  int o4 = tid & 7;
  const float4* vb = v4 + (size_t)(b*9)*SS*32 + g*8 + o4;
  float4 bias = b14[g*8 + o4];
  float4* y1t4 = (float4*)y1t;
  for(int task = tid; task < 2592; task += 256){
    int pp = task >> 3;
    int py = pp/18, px = pp%18;
    int gy = y0p - 1 + py, gx = x0p - 1 + px;
    float4 acc = {0.f,0.f,0.f,0.f};
    if(gy>=0 && gy<256 && gx>=0 && gx<256){
      acc = bias;
      #pragma unroll
      for(int k=0;k<9;k++){
        int sidx = segl[(py + k/3)*20 + (px + k%3)];
        if(sidx >= 0){
          float4 vv = vb[(k*SS + sidx)*32];
          acc.x += vv.x; acc.y += vv.y; acc.z += vv.z; acc.w += vv.w;
        }
      }
      acc.x = lrelu(acc.x); acc.y = lrelu(acc.y); acc.z = lrelu(acc.z); acc.w = lrelu(acc.w);
    }
    y1t4[pp*9 + o4] = acc;
  }
  __syncthreads();
  int tx = tid & 15, ty = tid >> 4;
  float s0 = 0.f, s1v = 0.f, s2 = 0.f;
  #pragma unroll
  for(int k=0;k<9;k++){
    int pp = (ty + k/3)*18 + (tx + k%3);
    #pragma unroll
    for(int sg=0;sg<8;sg++){
      float4 yv = y1t4[pp*9 + sg];
      int ci = sg*4;
      s0 += w2l[(0*32+ci+0)*9+k]*yv.x + w2l[(0*32+ci+1)*9+k]*yv.y
          + w2l[(0*32+ci+2)*9+k]*yv.z + w2l[(0*32+ci+3)*9+k]*yv.w;
      s1v+= w2l[(1*32+ci+0)*9+k]*yv.x + w2l[(1*32+ci+1)*9+k]*yv.y
          + w2l[(1*32+ci+2)*9+k]*yv.z + w2l[(1*32+ci+3)*9+k]*yv.w;
      s2 += w2l[(2*32+ci+0)*9+k]*yv.x + w2l[(2*32+ci+1)*9+k]*yv.y
          + w2l[(2*32+ci+2)*9+k]*yv.z + w2l[(2*32+ci+3)*9+k]*yv.w;
    }
  }
  int nidx = (y0p+ty)*256 + x0p + tx;
  atomicAdd(&y2[(b*3+0)*NPIX + nidx], s0);
  atomicAdd(&y2[(b*3+1)*NPIX + nidx], s1v);
  atomicAdd(&y2[(b*3+2)*NPIX + nidx], s2);
}

// ---- per (b,channel) sum & sumsq, parallel chunks with f64 atomics ----
__global__ void k_stats(const float* __restrict__ y2, double* __restrict__ stats){
  int bc = blockIdx.x;     // 12
  int chunk = blockIdx.y;  // 8
  const float* p = y2 + (size_t)bc*NPIX + chunk*8192;
  int t = threadIdx.x;
  double s=0.0, q=0.0;
  for(int i=t;i<8192;i+=256){ double vv = (double)p[i]; s+=vv; q+=vv*vv; }
  __shared__ double rs[256], rq[256];
  rs[t]=s; rq[t]=q; __syncthreads();
  for(int st=128; st; st>>=1){ if(t<st){rs[t]+=rs[t+st]; rq[t]+=rq[t+st];} __syncthreads(); }
  if(t==0){ atomicAdd(&stats[bc*2], rs[0]); atomicAdd(&stats[bc*2+1], rq[0]); }
}

// ---- instance norm + tanh ----
__global__ void k_norm(const float* __restrict__ y2, const double* __restrict__ stats,
                       float* __restrict__ out){
  int idx = blockIdx.x*256+threadIdx.x;
  int bu = idx >> 16;
  double mu  = stats[bu*2+0] * (1.0/65536.0);
  double ex2 = stats[bu*2+1] * (1.0/65536.0);
  double var = ex2 - mu*mu;
  float inv = (float)(1.0/sqrt(var + 1e-5));
  float mf = (float)mu;
  out[idx] = tanhf((y2[idx]-mf)*inv);
}

extern "C" void kernel_launch(void* const* d_in, const int* in_sizes, int n_in,
                              void* d_out, int out_size, void* d_ws, size_t ws_size,
                              hipStream_t stream) {
  const float* z   = (const float*)d_in[0];
  const float* img = (const float*)d_in[1];
  const int*   seg = (const int*)d_in[2];
  const float* A   = (const float*)d_in[3];
  const float* pw  = (const float*)d_in[4];
  const float* pb  = (const float*)d_in[5];
  const float* bw  = (const float*)d_in[6];
  const float* bb  = (const float*)d_in[7];
  const float* a1w = (const float*)d_in[8];
  const float* a1b = (const float*)d_in[9];
  const float* a2w = (const float*)d_in[10];
  const float* a2b = (const float*)d_in[11];
  const float* w1  = (const float*)d_in[12];
  const float* b1  = (const float*)d_in[13];
  const float* w2  = (const float*)d_in[14];
  const float* b2  = (const float*)d_in[15]; (void)b2; // cancels under InstanceNorm
  float* out = (float*)d_out;

  float* ws = (float*)d_ws;
  float* segsum = ws;                    // 3072
  float* counts = ws + 3072;             // 1024
  float* m      = ws + 4096;             // 1024
  float* s1g    = ws + 5120;             // 2048
  double* stats = (double*)(ws + 7168);  // 24 doubles -> 7216, pad to 7296
  float* xp  = ws + 7296;                // 262144
  float* h2  = xp + 262144;              // 262144
  float* At  = h2 + 262144;              // 262144
  float* wT  = At + 262144;              // 294912
  float* v   = wT + 294912;              // 1179648
  float* y2  = v + 1179648;              // 786432  (end ~12.2 MB)

  hipMemsetAsync(ws, 0, 7296*sizeof(float), stream);     // sums + stats
  hipMemsetAsync(y2, 0, 786432*sizeof(float), stream);   // conv2 accumulator

  float sProj = (float)sqrt(2.0/131.0);
  float s256  = (float)sqrt(2.0/256.0);
  float s512  = (float)sqrt(2.0/512.0);

  k_pool <<<256, 256, 0, stream>>>(img, seg, segsum, counts);
  k_prep1<<<2176, 256, 0, stream>>>(A, w1, At, wT);
  k_x0   <<<dim3(4,64,4), 256, 0, stream>>>(segsum, counts, z, pw, pb, sProj, xp);

  for(int blk=0; blk<NBLKS; blk++){
    k_gemm<<<dim3(64,4), 512, 0, stream>>>(xp, bw + blk*GCH*GCH, bb + blk*GCH,
                                           At, s256, h2, m);
    k_s1  <<<32, 256, 0, stream>>>(m, a1w + blk*512*GCH, a1b + blk*512, s256, s1g);
    k_s2apply<<<32, 256, 0, stream>>>(s1g, a2w + blk*512*512, a2b + blk*512,
                                      h2, s512, xp);
  }

  k_v   <<<dim3(32,9,4), 256, 0, stream>>>(xp, (const float4*)wT, (float4*)v);
  k_conv<<<dim3(16,16,16), 256, 0, stream>>>((const float4*)v, seg, (const float4*)b1, w2, y2);
  k_stats<<<dim3(12,8), 256, 0, stream>>>(y2, stats);
  k_norm<<<3072, 256, 0, stream>>>(y2, stats, out);
}

// Round 6
// 470.944 us; speedup vs baseline: 2.1086x; 1.7202x over previous
//
#include <hip/hip_runtime.h>
#include <cmath>

#define BB 4
#define SS 256
#define ZDIM 128
#define GCH 256
#define NBLKS 8
#define NPIX 65536   // 256*256
#define U1C 128      // GC/2

__device__ __forceinline__ float lrelu(float x){ return x >= 0.f ? x : 0.2f*x; }

// ---- segment mean pooling (LDS histogram, then global atomics) ----
__global__ void k_pool(const float* __restrict__ img, const int* __restrict__ seg,
                       float* __restrict__ segsum, float* __restrict__ counts){
  __shared__ float ls[SS*4];
  int t = threadIdx.x;
  for(int j=t;j<SS*4;j+=256) ls[j]=0.f;
  __syncthreads();
  int b = blockIdx.x >> 6;            // 64 blocks per batch
  int base = blockIdx.x*1024;
  for(int it=0; it<4; it++){
    int idx = base + it*256 + t;
    int n = idx & (NPIX-1);
    int s = seg[idx];
    atomicAdd(&ls[s*4+0], img[(b*3+0)*NPIX+n]);
    atomicAdd(&ls[s*4+1], img[(b*3+1)*NPIX+n]);
    atomicAdd(&ls[s*4+2], img[(b*3+2)*NPIX+n]);
    atomicAdd(&ls[s*4+3], 1.0f);
  }
  __syncthreads();
  for(int j=t;j<SS*4;j+=256){
    int s = j>>2, c = j&3;
    float vv = ls[j];
    if(vv != 0.f){
      if(c<3) atomicAdd(&segsum[(b*SS+s)*3+c], vv);
      else    atomicAdd(&counts[b*SS+s], vv);
    }
  }
}

// ---- tiled transpose of A: At[b][j][i] = A[b][i][j] ----
__global__ __launch_bounds__(256) void k_prepA(const float* __restrict__ A,
                                               float* __restrict__ At){
  __shared__ float t[32][33];
  int b = blockIdx.z;
  int bx = blockIdx.x*32, by = blockIdx.y*32;
  int lx = threadIdx.x & 31, ly4 = (threadIdx.x >> 5)*4;
  #pragma unroll
  for(int r=0;r<4;r++)
    t[ly4+r][lx] = A[(b<<16) + ((by+ly4+r)<<8) + bx + lx];
  __syncthreads();
  #pragma unroll
  for(int r=0;r<4;r++)
    At[(b<<16) + ((bx+ly4+r)<<8) + by + lx] = t[lx][ly4+r];
}

// ---- transpose up1_w: wT[(k*256+c)*128+o] = w1[(o*256+c)*9+k] ----
__global__ void k_prepW(const float* __restrict__ w1, float* __restrict__ wT){
  int idx = blockIdx.x*256 + threadIdx.x;   // 294912
  int o = idx & 127; int r = idx >> 7; int c = r & 255; int k = r >> 8;
  wT[idx] = w1[(o*GCH + c)*9 + k];
}

// ---- x0 = WSproj(concat(feats, z)) -> xp (block-0 input, no AdaIN) ----
__global__ void k_x0(const float* __restrict__ segsum, const float* __restrict__ counts,
                     const float* __restrict__ z, const float* __restrict__ pw,
                     const float* __restrict__ pb, float sc, float* __restrict__ xp){
  int i = blockIdx.x*64 + (threadIdx.x & 63);
  int o = blockIdx.y*4  + (threadIdx.x >> 6);
  int b = blockIdx.z;
  float cnt = counts[b*SS+i] + 1e-6f;
  float f0 = segsum[(b*SS+i)*3+0]/cnt;
  float f1 = segsum[(b*SS+i)*3+1]/cnt;
  float f2 = segsum[(b*SS+i)*3+2]/cnt;
  const float* wr = pw + o*131;
  float acc = wr[0]*f0 + wr[1]*f1 + wr[2]*f2;
  const float* zb = z + b*ZDIM;
  #pragma unroll 8
  for(int j=0;j<ZDIM;j++) acc += wr[3+j]*zb[j];
  xp[(b*GCH+o)*SS + i] = acc*sc + pb[o];
}

// ---- gemm + A-propagation + node mean: 4 channels per block, 512 threads ----
__global__ __launch_bounds__(512) void k_gemm(const float* __restrict__ xp,
        const float* __restrict__ bw, const float* __restrict__ bb,
        const float* __restrict__ At, float sc,
        float* __restrict__ h2, float* __restrict__ m){
  int c0 = blockIdx.x*4;
  int b  = blockIdx.y;
  int j  = threadIdx.x & 255;
  int half = threadIdx.x >> 8;
  __shared__ float wl[4][256];
  __shared__ float h1l[4][260];
  __shared__ float red[4][4];
  wl[half*2+0][j] = bw[(c0+half*2+0)*GCH + j];
  wl[half*2+1][j] = bw[(c0+half*2+1)*GCH + j];
  __syncthreads();
  const float* xb = xp + b*GCH*SS + j;
  float a0 = 0.f, a1 = 0.f;
  int ch = half*2;
  #pragma unroll 8
  for(int k=0;k<GCH;k++){
    float xv = xb[k*SS];
    a0 += wl[ch][k]*xv;
    a1 += wl[ch+1][k]*xv;
  }
  h1l[ch][j]   = a0*sc + bb[c0+ch];
  h1l[ch+1][j] = a1*sc + bb[c0+ch+1];
  __syncthreads();
  const float* ab = At + b*SS*SS + j;
  float r0 = 0.f, r1 = 0.f;
  #pragma unroll 2
  for(int jj=0;jj<SS;jj+=4){
    float4 h0 = *(const float4*)&h1l[ch][jj];
    float4 h1v = *(const float4*)&h1l[ch+1][jj];
    float av0 = ab[jj*SS], av1 = ab[(jj+1)*SS], av2 = ab[(jj+2)*SS], av3 = ab[(jj+3)*SS];
    r0 += h0.x*av0 + h0.y*av1 + h0.z*av2 + h0.w*av3;
    r1 += h1v.x*av0 + h1v.y*av1 + h1v.z*av2 + h1v.w*av3;
  }
  h2[(b*GCH+c0+ch)*SS + j]   = r0;
  h2[(b*GCH+c0+ch+1)*SS + j] = r1;
  float s0 = r0, s1v = r1;
  for(int off=32; off; off>>=1){ s0 += __shfl_down(s0,off); s1v += __shfl_down(s1v,off); }
  int w3 = (threadIdx.x >> 6) & 3;
  if((j&63)==0){ red[ch][w3] = s0; red[ch+1][w3] = s1v; }
  __syncthreads();
  if(threadIdx.x < 4)
    m[b*GCH + c0 + threadIdx.x] =
      (red[threadIdx.x][0]+red[threadIdx.x][1]+red[threadIdx.x][2]+red[threadIdx.x][3])*(1.f/256.f);
}

// ---- style layer 1: 32 blocks, 16 rows each, all 4 batches per row ----
__global__ __launch_bounds__(256) void k_s1(const float* __restrict__ m,
        const float* __restrict__ a1w, const float* __restrict__ a1b,
        float sc1, float* __restrict__ s1g){
  int q = blockIdx.x;               // 0..31
  int lane = threadIdx.x & 63, wv = threadIdx.x >> 6;
  float4 mv0 = *(const float4*)(m + 0*GCH + lane*4);
  float4 mv1 = *(const float4*)(m + 1*GCH + lane*4);
  float4 mv2 = *(const float4*)(m + 2*GCH + lane*4);
  float4 mv3 = *(const float4*)(m + 3*GCH + lane*4);
  #pragma unroll
  for(int r=0;r<4;r++){
    int row = q*16 + wv*4 + r;
    float4 w4 = *(const float4*)(a1w + row*GCH + lane*4);
    float p0 = w4.x*mv0.x + w4.y*mv0.y + w4.z*mv0.z + w4.w*mv0.w;
    float p1 = w4.x*mv1.x + w4.y*mv1.y + w4.z*mv1.z + w4.w*mv1.w;
    float p2 = w4.x*mv2.x + w4.y*mv2.y + w4.z*mv2.z + w4.w*mv2.w;
    float p3 = w4.x*mv3.x + w4.y*mv3.y + w4.z*mv3.z + w4.w*mv3.w;
    for(int off=32; off; off>>=1){
      p0 += __shfl_xor(p0,off); p1 += __shfl_xor(p1,off);
      p2 += __shfl_xor(p2,off); p3 += __shfl_xor(p3,off);
    }
    if(lane < 4){
      float p = lane==0 ? p0 : lane==1 ? p1 : lane==2 ? p2 : p3;
      s1g[lane*512 + row] = lrelu(p*sc1 + a1b[row]);
    }
  }
}

// ---- style layer 2 + AdaIN apply: 32 blocks, 8 channels each, all batches ----
__global__ __launch_bounds__(256) void k_s2apply(const float* __restrict__ s1g,
        const float* __restrict__ a2w, const float* __restrict__ a2b,
        const float* __restrict__ h2, float sc2, float* __restrict__ xp){
  int q = blockIdx.x;               // 0..31 -> channels q*8..q*8+7
  int tid = threadIdx.x;
  int lane = tid & 63, wv = tid >> 6;
  __shared__ float gbl[4][16];      // [b][0..7]=gamma, [8..15]=beta
  float4 sa[4], sb[4];
  #pragma unroll
  for(int b=0;b<4;b++){
    sa[b] = *(const float4*)(s1g + b*512 + lane*8);
    sb[b] = *(const float4*)(s1g + b*512 + lane*8 + 4);
  }
  #pragma unroll
  for(int r=0;r<4;r++){
    int ridx = wv*4 + r;            // 0..15
    int cc = ridx & 7;
    int t = (ridx < 8) ? (q*8 + cc) : (256 + q*8 + cc);
    const float* wr = a2w + t*512 + lane*8;
    float4 wa = *(const float4*)wr;
    float4 wb4 = *(const float4*)(wr+4);
    float p0 = wa.x*sa[0].x+wa.y*sa[0].y+wa.z*sa[0].z+wa.w*sa[0].w
             + wb4.x*sb[0].x+wb4.y*sb[0].y+wb4.z*sb[0].z+wb4.w*sb[0].w;
    float p1 = wa.x*sa[1].x+wa.y*sa[1].y+wa.z*sa[1].z+wa.w*sa[1].w
             + wb4.x*sb[1].x+wb4.y*sb[1].y+wb4.z*sb[1].z+wb4.w*sb[1].w;
    float p2 = wa.x*sa[2].x+wa.y*sa[2].y+wa.z*sa[2].z+wa.w*sa[2].w
             + wb4.x*sb[2].x+wb4.y*sb[2].y+wb4.z*sb[2].z+wb4.w*sb[2].w;
    float p3 = wa.x*sa[3].x+wa.y*sa[3].y+wa.z*sa[3].z+wa.w*sa[3].w
             + wb4.x*sb[3].x+wb4.y*sb[3].y+wb4.z*sb[3].z+wb4.w*sb[3].w;
    for(int off=32; off; off>>=1){
      p0 += __shfl_xor(p0,off); p1 += __shfl_xor(p1,off);
      p2 += __shfl_xor(p2,off); p3 += __shfl_xor(p3,off);
    }
    if(lane < 4){
      float p = lane==0 ? p0 : lane==1 ? p1 : lane==2 ? p2 : p3;
      gbl[lane][ridx] = p*sc2 + a2b[t];
    }
  }
  __syncthreads();
  int c0 = q*8;
  #pragma unroll
  for(int b=0;b<4;b++){
    #pragma unroll
    for(int cc=0;cc<8;cc++){
      float ga = gbl[b][cc], be = gbl[b][8+cc];
      float hv = h2[(b*GCH + c0+cc)*SS + tid];
      xp[(b*GCH + c0+cc)*SS + tid] = lrelu(ga*hv + be);
    }
  }
}

// ---- v[b][k][s][o] = sum_c wT[k][c][o] * xp[c][s] (xp already activated) ----
__global__ __launch_bounds__(256) void k_v(const float* __restrict__ xf,
        const float4* __restrict__ wT4, float4* __restrict__ v4){
  int s0 = blockIdx.x*8;
  int k  = blockIdx.y;
  int b  = blockIdx.z;
  int tid = threadIdx.x;
  __shared__ float xft[256][8];
  for(int t = tid; t < 2048; t += 256){
    int c = t>>3, ss = t&7;
    xft[c][ss] = xf[(b*GCH+c)*SS + s0 + ss];
  }
  __syncthreads();
  int og = tid & 31, s = tid >> 5;
  const float4* wb = wT4 + (size_t)k*GCH*32 + og;
  float4 acc = {0.f,0.f,0.f,0.f};
  #pragma unroll 4
  for(int c=0;c<GCH;c++){
    float xv = xft[c][s];
    float4 w = wb[c*32];
    acc.x += w.x*xv; acc.y += w.y*xv; acc.z += w.z*xv; acc.w += w.w*xv;
  }
  v4[((size_t)(b*9+k)*SS + s0 + s)*32 + og] = acc;
}

// ---- fused conv1-gather(float4) + conv2 partial, 8x8 tile, 32-ch group ----
// 1-D grid with XCD-batch locality: XCD x=bid&7 serves batch x>>1 only
__global__ __launch_bounds__(256) void k_conv(const float4* __restrict__ v4,
        const int* __restrict__ seg, const float4* __restrict__ b14,
        const float* __restrict__ w2, float* __restrict__ y2){
  __shared__ float y1t[32*101];     // [ci][pp]
  __shared__ int   segl[144];
  __shared__ float w2l[864];
  __shared__ float part[768];
  int bid = blockIdx.x;
  int x = bid & 7;
  int b = x >> 1;                         // 2 XCDs per batch
  int sub = ((bid >> 3) << 1) + (x & 1);  // 0..4095
  int g = sub & 3;
  int tile = sub >> 2;                    // 0..1023
  int x0p = (tile & 31)*8, y0p = (tile >> 5)*8;
  int tid = threadIdx.x;
  if(tid < 144){
    int r = tid/12, cc = tid%12;
    int gy = y0p - 2 + r, gx = x0p - 2 + cc;
    segl[tid] = (gy>=0 && gy<256 && gx>=0 && gx<256) ? seg[(b*256+gy)*256+gx] : -1;
  }
  for(int t=tid; t<864; t+=256){
    int oc = t/288, rem = t%288;
    w2l[t] = w2[oc*1152 + g*288 + rem];
  }
  __syncthreads();
  int o4 = tid & 7;
  const float4* vb = v4 + (size_t)(b*9)*SS*32 + g*8 + o4;
  float4 bias = b14[g*8 + o4];
  for(int task = tid; task < 800; task += 256){
    int pp = task >> 3;
    int py = pp/10, px = pp%10;
    int gy = y0p - 1 + py, gx = x0p - 1 + px;
    bool pix_ok = (gy>=0 && gy<256 && gx>=0 && gx<256);
    float4 acc = bias;
    #pragma unroll
    for(int k=0;k<9;k++){
      int sidx = segl[(py + k/3)*12 + (px + k%3)];
      int sidx0 = sidx < 0 ? 0 : sidx;
      float msk = sidx < 0 ? 0.f : 1.f;
      float4 vv = vb[(k*SS + sidx0)*32];
      acc.x += msk*vv.x; acc.y += msk*vv.y; acc.z += msk*vv.z; acc.w += msk*vv.w;
    }
    float4 val;
    val.x = pix_ok ? lrelu(acc.x) : 0.f;
    val.y = pix_ok ? lrelu(acc.y) : 0.f;
    val.z = pix_ok ? lrelu(acc.z) : 0.f;
    val.w = pix_ok ? lrelu(acc.w) : 0.f;
    int c0 = o4*4;
    y1t[(c0+0)*101+pp] = val.x;
    y1t[(c0+1)*101+pp] = val.y;
    y1t[(c0+2)*101+pp] = val.z;
    y1t[(c0+3)*101+pp] = val.w;
  }
  __syncthreads();
  int pxo = tid & 63, sg = tid >> 6;
  int ty = pxo >> 3, tx = pxo & 7;
  float p0=0.f,p1=0.f,p2=0.f;
  for(int k=0;k<9;k++){
    int pp0 = (ty + k/3)*10 + (tx + k%3);
    #pragma unroll
    for(int cc=0;cc<8;cc++){
      int ci = sg*8+cc;
      float yv = y1t[ci*101 + pp0];
      p0 += w2l[(0*32+ci)*9+k]*yv;
      p1 += w2l[(1*32+ci)*9+k]*yv;
      p2 += w2l[(2*32+ci)*9+k]*yv;
    }
  }
  part[tid]     = p0;
  part[256+tid] = p1;
  part[512+tid] = p2;
  __syncthreads();
  if(tid < 64){
    float s0 = part[tid]    +part[tid+64]    +part[tid+128]    +part[tid+192];
    float s1 = part[256+tid]+part[256+tid+64]+part[256+tid+128]+part[256+tid+192];
    float s2 = part[512+tid]+part[512+tid+64]+part[512+tid+128]+part[512+tid+192];
    int gy = y0p + (tid>>3), gx = x0p + (tid&7);
    int nidx = gy*256+gx;
    atomicAdd(&y2[(b*3+0)*NPIX+nidx], s0);
    atomicAdd(&y2[(b*3+1)*NPIX+nidx], s1);
    atomicAdd(&y2[(b*3+2)*NPIX+nidx], s2);
  }
}

// ---- per (b,channel) sum & sumsq, parallel chunks with f64 atomics ----
__global__ void k_stats(const float* __restrict__ y2, double* __restrict__ stats){
  int bc = blockIdx.x;     // 12
  int chunk = blockIdx.y;  // 8
  const float* p = y2 + (size_t)bc*NPIX + chunk*8192;
  int t = threadIdx.x;
  double s=0.0, q=0.0;
  for(int i=t;i<8192;i+=256){ double vv = (double)p[i]; s+=vv; q+=vv*vv; }
  __shared__ double rs[256], rq[256];
  rs[t]=s; rq[t]=q; __syncthreads();
  for(int st=128; st; st>>=1){ if(t<st){rs[t]+=rs[t+st]; rq[t]+=rq[t+st];} __syncthreads(); }
  if(t==0){ atomicAdd(&stats[bc*2], rs[0]); atomicAdd(&stats[bc*2+1], rq[0]); }
}

// ---- instance norm + tanh ----
__global__ void k_norm(const float* __restrict__ y2, const double* __restrict__ stats,
                       float* __restrict__ out){
  int idx = blockIdx.x*256+threadIdx.x;
  int bu = idx >> 16;
  double mu  = stats[bu*2+0] * (1.0/65536.0);
  double ex2 = stats[bu*2+1] * (1.0/65536.0);
  double var = ex2 - mu*mu;
  float inv = (float)(1.0/sqrt(var + 1e-5));
  float mf = (float)mu;
  out[idx] = tanhf((y2[idx]-mf)*inv);
}

extern "C" void kernel_launch(void* const* d_in, const int* in_sizes, int n_in,
                              void* d_out, int out_size, void* d_ws, size_t ws_size,
                              hipStream_t stream) {
  const float* z   = (const float*)d_in[0];
  const float* img = (const float*)d_in[1];
  const int*   seg = (const int*)d_in[2];
  const float* A   = (const float*)d_in[3];
  const float* pw  = (const float*)d_in[4];
  const float* pb  = (const float*)d_in[5];
  const float* bw  = (const float*)d_in[6];
  const float* bb  = (const float*)d_in[7];
  const float* a1w = (const float*)d_in[8];
  const float* a1b = (const float*)d_in[9];
  const float* a2w = (const float*)d_in[10];
  const float* a2b = (const float*)d_in[11];
  const float* w1  = (const float*)d_in[12];
  const float* b1  = (const float*)d_in[13];
  const float* w2  = (const float*)d_in[14];
  const float* b2  = (const float*)d_in[15]; (void)b2; // cancels under InstanceNorm
  float* out = (float*)d_out;

  float* ws = (float*)d_ws;
  float* segsum = ws;                    // 3072
  float* counts = ws + 3072;             // 1024
  float* m      = ws + 4096;             // 1024
  float* s1g    = ws + 5120;             // 2048
  double* stats = (double*)(ws + 7168);  // 24 doubles -> 7216, pad to 7296
  float* xp  = ws + 7296;                // 262144
  float* h2  = xp + 262144;              // 262144
  float* At  = h2 + 262144;              // 262144
  float* wT  = At + 262144;              // 294912
  float* v   = wT + 294912;              // 1179648
  float* y2  = v + 1179648;              // 786432  (end ~12.2 MB)

  hipMemsetAsync(ws, 0, 7296*sizeof(float), stream);     // sums + stats
  hipMemsetAsync(y2, 0, 786432*sizeof(float), stream);   // conv2 accumulator

  float sProj = (float)sqrt(2.0/131.0);
  float s256  = (float)sqrt(2.0/256.0);
  float s512  = (float)sqrt(2.0/512.0);

  k_pool <<<256, 256, 0, stream>>>(img, seg, segsum, counts);
  k_prepA<<<dim3(8,8,4), 256, 0, stream>>>(A, At);
  k_prepW<<<1152, 256, 0, stream>>>(w1, wT);
  k_x0   <<<dim3(4,64,4), 256, 0, stream>>>(segsum, counts, z, pw, pb, sProj, xp);

  for(int blk=0; blk<NBLKS; blk++){
    k_gemm<<<dim3(64,4), 512, 0, stream>>>(xp, bw + blk*GCH*GCH, bb + blk*GCH,
                                           At, s256, h2, m);
    k_s1  <<<32, 256, 0, stream>>>(m, a1w + blk*512*GCH, a1b + blk*512, s256, s1g);
    k_s2apply<<<32, 256, 0, stream>>>(s1g, a2w + blk*512*512, a2b + blk*512,
                                      h2, s512, xp);
  }

  k_v   <<<dim3(32,9,4), 256, 0, stream>>>(xp, (const float4*)wT, (float4*)v);
  k_conv<<<16384, 256, 0, stream>>>((const float4*)v, seg, (const float4*)b1, w2, y2);
  k_stats<<<dim3(12,8), 256, 0, stream>>>(y2, stats);
  k_norm<<<3072, 256, 0, stream>>>(y2, stats, out);
}

// Round 7
// 408.735 us; speedup vs baseline: 2.4295x; 1.1522x over previous
//
#include <hip/hip_runtime.h>
#include <cmath>

#define BB 4
#define SS 256
#define ZDIM 128
#define GCH 256
#define NBLKS 8
#define NPIX 65536   // 256*256
#define U1C 128      // GC/2

__device__ __forceinline__ float lrelu(float x){ return x >= 0.f ? x : 0.2f*x; }

// ---- segment mean pooling (LDS histogram, then global atomics) ----
__global__ void k_pool(const float* __restrict__ img, const int* __restrict__ seg,
                       float* __restrict__ segsum, float* __restrict__ counts){
  __shared__ float ls[SS*4];
  int t = threadIdx.x;
  for(int j=t;j<SS*4;j+=256) ls[j]=0.f;
  __syncthreads();
  int b = blockIdx.x >> 6;            // 64 blocks per batch
  int base = blockIdx.x*1024;
  for(int it=0; it<4; it++){
    int idx = base + it*256 + t;
    int n = idx & (NPIX-1);
    int s = seg[idx];
    atomicAdd(&ls[s*4+0], img[(b*3+0)*NPIX+n]);
    atomicAdd(&ls[s*4+1], img[(b*3+1)*NPIX+n]);
    atomicAdd(&ls[s*4+2], img[(b*3+2)*NPIX+n]);
    atomicAdd(&ls[s*4+3], 1.0f);
  }
  __syncthreads();
  for(int j=t;j<SS*4;j+=256){
    int s = j>>2, c = j&3;
    float vv = ls[j];
    if(vv != 0.f){
      if(c<3) atomicAdd(&segsum[(b*SS+s)*3+c], vv);
      else    atomicAdd(&counts[b*SS+s], vv);
    }
  }
}

// ---- tiled transpose of A: At[b][j][i] = A[b][i][j] ----
__global__ __launch_bounds__(256) void k_prepA(const float* __restrict__ A,
                                               float* __restrict__ At){
  __shared__ float t[32][33];
  int b = blockIdx.z;
  int bx = blockIdx.x*32, by = blockIdx.y*32;
  int lx = threadIdx.x & 31, ly4 = (threadIdx.x >> 5)*4;
  #pragma unroll
  for(int r=0;r<4;r++)
    t[ly4+r][lx] = A[(b<<16) + ((by+ly4+r)<<8) + bx + lx];
  __syncthreads();
  #pragma unroll
  for(int r=0;r<4;r++)
    At[(b<<16) + ((bx+ly4+r)<<8) + by + lx] = t[lx][ly4+r];
}

// ---- transpose up1_w and repack w2 for scalar loads ----
// wT[(k*256+c)*128+o] = w1[(o*256+c)*9+k]
// w2t[((k*4+g)*4+sg)*24 + oc*8 + cc] = w2[oc*1152 + (g*32+sg*8+cc)*9 + k]
__global__ void k_prepW(const float* __restrict__ w1, const float* __restrict__ w2,
                        float* __restrict__ wT, float* __restrict__ w2t){
  int idx = blockIdx.x*256 + threadIdx.x;
  if(idx < 294912){
    int o = idx & 127; int r = idx >> 7; int c = r & 255; int k = r >> 8;
    wT[idx] = w1[(o*GCH + c)*9 + k];
  } else if(idx < 294912 + 3456){
    int t = idx - 294912;
    int cc = t & 7;
    int oc = (t >> 3) % 3;
    int sg = (t / 24) & 3;
    int g  = (t / 96) & 3;
    int k  = t / 384;
    w2t[t] = w2[oc*1152 + (g*32 + sg*8 + cc)*9 + k];
  }
}

// ---- x0 = WSproj(concat(feats, z)) -> xp ----
__global__ void k_x0(const float* __restrict__ segsum, const float* __restrict__ counts,
                     const float* __restrict__ z, const float* __restrict__ pw,
                     const float* __restrict__ pb, float sc, float* __restrict__ xp){
  int i = blockIdx.x*64 + (threadIdx.x & 63);
  int o = blockIdx.y*4  + (threadIdx.x >> 6);
  int b = blockIdx.z;
  float cnt = counts[b*SS+i] + 1e-6f;
  float f0 = segsum[(b*SS+i)*3+0]/cnt;
  float f1 = segsum[(b*SS+i)*3+1]/cnt;
  float f2 = segsum[(b*SS+i)*3+2]/cnt;
  const float* wr = pw + o*131;
  float acc = wr[0]*f0 + wr[1]*f1 + wr[2]*f2;
  const float* zb = z + b*ZDIM;
  #pragma unroll 8
  for(int j=0;j<ZDIM;j++) acc += wr[3+j]*zb[j];
  xp[(b*GCH+o)*SS + i] = acc*sc + pb[o];
}

// ---- gemm + A-propagation + node mean: 4 channels per block, 512 threads ----
__global__ __launch_bounds__(512) void k_gemm(const float* __restrict__ xp,
        const float* __restrict__ bw, const float* __restrict__ bb,
        const float* __restrict__ At, float sc,
        float* __restrict__ h2, float* __restrict__ m){
  int c0 = blockIdx.x*4;
  int b  = blockIdx.y;
  int j  = threadIdx.x & 255;
  int half = threadIdx.x >> 8;
  __shared__ float wl[4][256];
  __shared__ float h1l[4][260];
  __shared__ float red[4][4];
  wl[half*2+0][j] = bw[(c0+half*2+0)*GCH + j];
  wl[half*2+1][j] = bw[(c0+half*2+1)*GCH + j];
  __syncthreads();
  const float* xb = xp + b*GCH*SS + j;
  float a0 = 0.f, a1 = 0.f;
  int ch = half*2;
  #pragma unroll 8
  for(int k=0;k<GCH;k++){
    float xv = xb[k*SS];
    a0 += wl[ch][k]*xv;
    a1 += wl[ch+1][k]*xv;
  }
  h1l[ch][j]   = a0*sc + bb[c0+ch];
  h1l[ch+1][j] = a1*sc + bb[c0+ch+1];
  __syncthreads();
  const float* ab = At + b*SS*SS + j;
  float r0 = 0.f, r1 = 0.f;
  #pragma unroll 2
  for(int jj=0;jj<SS;jj+=4){
    float4 h0 = *(const float4*)&h1l[ch][jj];
    float4 h1v = *(const float4*)&h1l[ch+1][jj];
    float av0 = ab[jj*SS], av1 = ab[(jj+1)*SS], av2 = ab[(jj+2)*SS], av3 = ab[(jj+3)*SS];
    r0 += h0.x*av0 + h0.y*av1 + h0.z*av2 + h0.w*av3;
    r1 += h1v.x*av0 + h1v.y*av1 + h1v.z*av2 + h1v.w*av3;
  }
  h2[(b*GCH+c0+ch)*SS + j]   = r0;
  h2[(b*GCH+c0+ch+1)*SS + j] = r1;
  float s0 = r0, s1v = r1;
  for(int off=32; off; off>>=1){ s0 += __shfl_down(s0,off); s1v += __shfl_down(s1v,off); }
  int w3 = (threadIdx.x >> 6) & 3;
  if((j&63)==0){ red[ch][w3] = s0; red[ch+1][w3] = s1v; }
  __syncthreads();
  if(threadIdx.x < 4)
    m[b*GCH + c0 + threadIdx.x] =
      (red[threadIdx.x][0]+red[threadIdx.x][1]+red[threadIdx.x][2]+red[threadIdx.x][3])*(1.f/256.f);
}

// ---- fused style L1 + L2 + AdaIN apply: 32 blocks x 512 threads ----
// Each block computes the FULL s1 (redundant, parallel) then its 16 gamma/beta
// rows (channels q*8..q*8+7) and applies AdaIN+leaky for those channels.
__global__ __launch_bounds__(512) void k_s12(const float* __restrict__ m,
        const float* __restrict__ a1w, const float* __restrict__ a1b,
        const float* __restrict__ a2w, const float* __restrict__ a2b,
        const float* __restrict__ h2, float sc1, float sc2, float* __restrict__ xp){
  int q = blockIdx.x;               // 0..31
  int tid = threadIdx.x;
  int lane = tid & 63, wv = tid >> 6;      // wv 0..7
  int grp = lane >> 3, ll = lane & 7;
  __shared__ float4 ml4[256];       // m: [b*64 + i]
  __shared__ float s1l[4][512];     // s1 stored at [(row&7)*64 + (row>>3)]
  __shared__ float gbl[4][16];
  if(tid < 256) ml4[tid] = ((const float4*)m)[tid];
  __syncthreads();
  // phase A: s1 rows, 8-lane group per row, 8 passes
  #pragma unroll 2
  for(int pass=0; pass<8; pass++){
    int row = wv*64 + pass*8 + grp;
    const float4* ar = (const float4*)(a1w + row*GCH) + ll;
    float p0=0.f,p1=0.f,p2=0.f,p3=0.f;
    #pragma unroll
    for(int j=0;j<8;j++){
      float4 w4 = ar[j*8];
      float4 m0 = ml4[0*64 + j*8 + ll];
      float4 m1 = ml4[1*64 + j*8 + ll];
      float4 m2 = ml4[2*64 + j*8 + ll];
      float4 m3 = ml4[3*64 + j*8 + ll];
      p0 += w4.x*m0.x + w4.y*m0.y + w4.z*m0.z + w4.w*m0.w;
      p1 += w4.x*m1.x + w4.y*m1.y + w4.z*m1.z + w4.w*m1.w;
      p2 += w4.x*m2.x + w4.y*m2.y + w4.z*m2.z + w4.w*m2.w;
      p3 += w4.x*m3.x + w4.y*m3.y + w4.z*m3.z + w4.w*m3.w;
    }
    #pragma unroll
    for(int off=1; off<8; off<<=1){
      p0 += __shfl_xor(p0,off); p1 += __shfl_xor(p1,off);
      p2 += __shfl_xor(p2,off); p3 += __shfl_xor(p3,off);
    }
    if(ll == 0){
      float bv = a1b[row];
      int sidx = ((row & 7) << 6) + (row >> 3);
      s1l[0][sidx] = lrelu(p0*sc1 + bv);
      s1l[1][sidx] = lrelu(p1*sc1 + bv);
      s1l[2][sidx] = lrelu(p2*sc1 + bv);
      s1l[3][sidx] = lrelu(p3*sc1 + bv);
    }
  }
  __syncthreads();
  // phase B: 16 s2 rows; lane holds s1[lane*8+j] (conflict-free transposed reads)
  float sA[4][8];
  #pragma unroll
  for(int b=0;b<4;b++)
    #pragma unroll
    for(int j=0;j<8;j++) sA[b][j] = s1l[b][j*64 + lane];
  #pragma unroll
  for(int r=0;r<2;r++){
    int ridx = wv*2 + r;            // 0..15
    int cc = ridx & 7;
    int t = (ridx < 8) ? (q*8 + cc) : (256 + q*8 + cc);
    const float* wr = a2w + t*512 + lane*8;
    float4 wa = *(const float4*)wr;
    float4 wb4 = *(const float4*)(wr+4);
    float p0 = wa.x*sA[0][0]+wa.y*sA[0][1]+wa.z*sA[0][2]+wa.w*sA[0][3]
             + wb4.x*sA[0][4]+wb4.y*sA[0][5]+wb4.z*sA[0][6]+wb4.w*sA[0][7];
    float p1 = wa.x*sA[1][0]+wa.y*sA[1][1]+wa.z*sA[1][2]+wa.w*sA[1][3]
             + wb4.x*sA[1][4]+wb4.y*sA[1][5]+wb4.z*sA[1][6]+wb4.w*sA[1][7];
    float p2 = wa.x*sA[2][0]+wa.y*sA[2][1]+wa.z*sA[2][2]+wa.w*sA[2][3]
             + wb4.x*sA[2][4]+wb4.y*sA[2][5]+wb4.z*sA[2][6]+wb4.w*sA[2][7];
    float p3 = wa.x*sA[3][0]+wa.y*sA[3][1]+wa.z*sA[3][2]+wa.w*sA[3][3]
             + wb4.x*sA[3][4]+wb4.y*sA[3][5]+wb4.z*sA[3][6]+wb4.w*sA[3][7];
    for(int off=32; off; off>>=1){
      p0 += __shfl_xor(p0,off); p1 += __shfl_xor(p1,off);
      p2 += __shfl_xor(p2,off); p3 += __shfl_xor(p3,off);
    }
    if(lane < 4){
      float p = lane==0 ? p0 : lane==1 ? p1 : lane==2 ? p2 : p3;
      gbl[lane][ridx] = p*sc2 + a2b[t];
    }
  }
  __syncthreads();
  // apply AdaIN + leaky for channels q*8..q*8+7 (512 threads: half-split on cc)
  int c0 = q*8;
  int jn = tid & 255;
  int hf = tid >> 8;
  #pragma unroll
  for(int b=0;b<4;b++){
    #pragma unroll
    for(int c2=0;c2<4;c2++){
      int cc = hf*4 + c2;
      float ga = gbl[b][cc], be = gbl[b][8+cc];
      float hv = h2[(b*GCH + c0+cc)*SS + jn];
      xp[(b*GCH + c0+cc)*SS + jn] = lrelu(ga*hv + be);
    }
  }
}

// ---- v[b][k][s][o] = sum_c wT[k][c][o] * xp[c][s], wT staged in LDS ----
__global__ __launch_bounds__(256) void k_v(const float* __restrict__ xf,
        const float4* __restrict__ wT4, float4* __restrict__ v4){
  int s0 = blockIdx.x*16;           // grid (16,9,4)
  int k  = blockIdx.y;
  int b  = blockIdx.z;
  int tid = threadIdx.x;
  __shared__ float4 wl[64][33];
  __shared__ float xft[256][16];
  for(int t = tid; t < 1024; t += 256){
    int c = t>>2, sf = t&3;
    *(float4*)&xft[c][sf*4] = *(const float4*)(xf + (b*GCH+c)*SS + s0 + sf*4);
  }
  int og = tid & 31, sh = tid >> 5;  // sh 0..7
  const float4* wb = wT4 + (size_t)k*GCH*32;
  float4 a0 = {0.f,0.f,0.f,0.f}, a1 = {0.f,0.f,0.f,0.f};
  for(int ct=0; ct<4; ct++){
    __syncthreads();
    for(int t = tid; t < 2048; t += 256){
      int cc = t>>5, o = t&31;
      wl[cc][o] = wb[(ct*64+cc)*32 + o];
    }
    __syncthreads();
    #pragma unroll 4
    for(int cc=0;cc<64;cc++){
      float4 w = wl[cc][og];
      int c = ct*64+cc;
      float x0v = xft[c][sh];
      float x1v = xft[c][8+sh];
      a0.x += w.x*x0v; a0.y += w.y*x0v; a0.z += w.z*x0v; a0.w += w.w*x0v;
      a1.x += w.x*x1v; a1.y += w.y*x1v; a1.z += w.z*x1v; a1.w += w.w*x1v;
    }
  }
  size_t base = (size_t)(b*9+k)*SS + s0;
  v4[(base + sh)*32 + og]     = a0;
  v4[(base + 8 + sh)*32 + og] = a1;
}

// ---- fused conv1-gather(float4) + conv2 (scalar weights), 8x8 tile ----
// 1-D grid with XCD-batch locality: XCD x=bid&7 serves batch x>>1 only
__global__ __launch_bounds__(256) void k_conv(const float4* __restrict__ v4,
        const int* __restrict__ seg, const float4* __restrict__ b14,
        const float* __restrict__ w2t, float* __restrict__ y2){
  __shared__ float4 y1t4[100*9];    // [pp][8 ch-f4 + pad]
  __shared__ int   segl[144];
  __shared__ float part[768];
  int bid = blockIdx.x;
  int x = bid & 7;
  int b = x >> 1;
  int sub = ((bid >> 3) << 1) + (x & 1);  // 0..4095
  int g = sub & 3;
  int tile = sub >> 2;
  int x0p = (tile & 31)*8, y0p = (tile >> 5)*8;
  int tid = threadIdx.x;
  if(tid < 144){
    int r = tid/12, cc = tid%12;
    int gy = y0p - 2 + r, gx = x0p - 2 + cc;
    segl[tid] = (gy>=0 && gy<256 && gx>=0 && gx<256) ? seg[(b*256+gy)*256+gx] : -1;
  }
  __syncthreads();
  int o4 = tid & 7;
  const float4* vb = v4 + (size_t)(b*9)*SS*32 + g*8 + o4;
  float4 bias = b14[g*8 + o4];
  bool interior = (x0p >= 8 && x0p <= 240 && y0p >= 8 && y0p <= 240);
  if(interior){
    for(int task = tid; task < 800; task += 256){
      int pp = task >> 3;
      int py = pp/10, px = pp - py*10;
      float4 acc = bias;
      #pragma unroll
      for(int k=0;k<9;k++){
        int sidx = segl[(py + k/3)*12 + (px + k%3)];
        float4 vv = vb[(k*SS + sidx)*32];
        acc.x += vv.x; acc.y += vv.y; acc.z += vv.z; acc.w += vv.w;
      }
      float4 val;
      val.x = lrelu(acc.x); val.y = lrelu(acc.y);
      val.z = lrelu(acc.z); val.w = lrelu(acc.w);
      y1t4[pp*9 + o4] = val;
    }
  } else {
    for(int task = tid; task < 800; task += 256){
      int pp = task >> 3;
      int py = pp/10, px = pp - py*10;
      int gy = y0p - 1 + py, gx = x0p - 1 + px;
      bool pix_ok = (gy>=0 && gy<256 && gx>=0 && gx<256);
      float4 acc = bias;
      #pragma unroll
      for(int k=0;k<9;k++){
        int sidx = segl[(py + k/3)*12 + (px + k%3)];
        int sidx0 = sidx < 0 ? 0 : sidx;
        float msk = sidx < 0 ? 0.f : 1.f;
        float4 vv = vb[(k*SS + sidx0)*32];
        acc.x += msk*vv.x; acc.y += msk*vv.y; acc.z += msk*vv.z; acc.w += msk*vv.w;
      }
      float4 val;
      val.x = pix_ok ? lrelu(acc.x) : 0.f;
      val.y = pix_ok ? lrelu(acc.y) : 0.f;
      val.z = pix_ok ? lrelu(acc.z) : 0.f;
      val.w = pix_ok ? lrelu(acc.w) : 0.f;
      y1t4[pp*9 + o4] = val;
    }
  }
  __syncthreads();
  int pxo = tid & 63, sg = tid >> 6;
  int sgu = __builtin_amdgcn_readfirstlane(sg);
  const float* wk0 = w2t + (g*4 + sgu)*24;   // + k*384
  int ty = pxo >> 3, tx = pxo & 7;
  float p0=0.f,p1=0.f,p2=0.f;
  #pragma unroll
  for(int k=0;k<9;k++){
    int pp0 = (ty + k/3)*10 + (tx + k%3);
    float4 ya = y1t4[pp0*9 + sgu*2];
    float4 yb = y1t4[pp0*9 + sgu*2 + 1];
    const float* wk = wk0 + k*384;
    p0 += wk[0]*ya.x + wk[1]*ya.y + wk[2]*ya.z + wk[3]*ya.w
        + wk[4]*yb.x + wk[5]*yb.y + wk[6]*yb.z + wk[7]*yb.w;
    p1 += wk[8]*ya.x + wk[9]*ya.y + wk[10]*ya.z + wk[11]*ya.w
        + wk[12]*yb.x + wk[13]*yb.y + wk[14]*yb.z + wk[15]*yb.w;
    p2 += wk[16]*ya.x + wk[17]*ya.y + wk[18]*ya.z + wk[19]*ya.w
        + wk[20]*yb.x + wk[21]*yb.y + wk[22]*yb.z + wk[23]*yb.w;
  }
  part[tid]     = p0;
  part[256+tid] = p1;
  part[512+tid] = p2;
  __syncthreads();
  if(tid < 64){
    float s0 = part[tid]    +part[tid+64]    +part[tid+128]    +part[tid+192];
    float s1 = part[256+tid]+part[256+tid+64]+part[256+tid+128]+part[256+tid+192];
    float s2 = part[512+tid]+part[512+tid+64]+part[512+tid+128]+part[512+tid+192];
    int gy = y0p + (tid>>3), gx = x0p + (tid&7);
    int nidx = gy*256+gx;
    atomicAdd(&y2[(b*3+0)*NPIX+nidx], s0);
    atomicAdd(&y2[(b*3+1)*NPIX+nidx], s1);
    atomicAdd(&y2[(b*3+2)*NPIX+nidx], s2);
  }
}

// ---- per (b,channel) sum & sumsq, parallel chunks with f64 atomics ----
__global__ void k_stats(const float* __restrict__ y2, double* __restrict__ stats){
  int bc = blockIdx.x;     // 12
  int chunk = blockIdx.y;  // 8
  const float* p = y2 + (size_t)bc*NPIX + chunk*8192;
  int t = threadIdx.x;
  double s=0.0, q=0.0;
  for(int i=t;i<8192;i+=256){ double vv = (double)p[i]; s+=vv; q+=vv*vv; }
  __shared__ double rs[256], rq[256];
  rs[t]=s; rq[t]=q; __syncthreads();
  for(int st=128; st; st>>=1){ if(t<st){rs[t]+=rs[t+st]; rq[t]+=rq[t+st];} __syncthreads(); }
  if(t==0){ atomicAdd(&stats[bc*2], rs[0]); atomicAdd(&stats[bc*2+1], rq[0]); }
}

// ---- instance norm + tanh ----
__global__ void k_norm(const float* __restrict__ y2, const double* __restrict__ stats,
                       float* __restrict__ out){
  int idx = blockIdx.x*256+threadIdx.x;
  int bu = idx >> 16;
  double mu  = stats[bu*2+0] * (1.0/65536.0);
  double ex2 = stats[bu*2+1] * (1.0/65536.0);
  double var = ex2 - mu*mu;
  float inv = (float)(1.0/sqrt(var + 1e-5));
  float mf = (float)mu;
  out[idx] = tanhf((y2[idx]-mf)*inv);
}

extern "C" void kernel_launch(void* const* d_in, const int* in_sizes, int n_in,
                              void* d_out, int out_size, void* d_ws, size_t ws_size,
                              hipStream_t stream) {
  const float* z   = (const float*)d_in[0];
  const float* img = (const float*)d_in[1];
  const int*   seg = (const int*)d_in[2];
  const float* A   = (const float*)d_in[3];
  const float* pw  = (const float*)d_in[4];
  const float* pb  = (const float*)d_in[5];
  const float* bw  = (const float*)d_in[6];
  const float* bb  = (const float*)d_in[7];
  const float* a1w = (const float*)d_in[8];
  const float* a1b = (const float*)d_in[9];
  const float* a2w = (const float*)d_in[10];
  const float* a2b = (const float*)d_in[11];
  const float* w1  = (const float*)d_in[12];
  const float* b1  = (const float*)d_in[13];
  const float* w2  = (const float*)d_in[14];
  const float* b2  = (const float*)d_in[15]; (void)b2; // cancels under InstanceNorm
  float* out = (float*)d_out;

  float* ws = (float*)d_ws;
  float* segsum = ws;                    // 3072
  float* counts = ws + 3072;             // 1024
  float* m      = ws + 4096;             // 1024
  double* stats = (double*)(ws + 5120);  // 24 doubles -> 5168, pad to 5248
  float* xp  = ws + 5248;                // 262144
  float* h2  = xp + 262144;              // 262144
  float* At  = h2 + 262144;              // 262144
  float* wT  = At + 262144;              // 294912
  float* v   = wT + 294912;              // 1179648
  float* y2  = v + 1179648;              // 786432
  float* w2t = y2 + 786432;              // 3456   (end ~12.2 MB)

  hipMemsetAsync(ws, 0, 5248*sizeof(float), stream);     // sums + stats
  hipMemsetAsync(y2, 0, 786432*sizeof(float), stream);   // conv2 accumulator

  float sProj = (float)sqrt(2.0/131.0);
  float s256  = (float)sqrt(2.0/256.0);
  float s512  = (float)sqrt(2.0/512.0);

  k_pool <<<256, 256, 0, stream>>>(img, seg, segsum, counts);
  k_prepA<<<dim3(8,8,4), 256, 0, stream>>>(A, At);
  k_prepW<<<1166, 256, 0, stream>>>(w1, w2, wT, w2t);
  k_x0   <<<dim3(4,64,4), 256, 0, stream>>>(segsum, counts, z, pw, pb, sProj, xp);

  for(int blk=0; blk<NBLKS; blk++){
    k_gemm<<<dim3(64,4), 512, 0, stream>>>(xp, bw + blk*GCH*GCH, bb + blk*GCH,
                                           At, s256, h2, m);
    k_s12 <<<32, 512, 0, stream>>>(m, a1w + blk*512*GCH, a1b + blk*512,
                                   a2w + blk*512*512, a2b + blk*512,
                                   h2, s256, s512, xp);
  }

  k_v   <<<dim3(16,9,4), 256, 0, stream>>>(xp, (const float4*)wT, (float4*)v);
  k_conv<<<16384, 256, 0, stream>>>((const float4*)v, seg, (const float4*)b1, w2t, y2);
  k_stats<<<dim3(12,8), 256, 0, stream>>>(y2, stats);
  k_norm<<<3072, 256, 0, stream>>>(y2, stats, out);
}